// Round 15
// baseline (194.116 us; speedup 1.0000x reference)
//
#include <hip/hip_runtime.h>
#include <hip/hip_bf16.h>
#include <math.h>
#include <stdint.h>

#define N_TOKENS 16384
#define DIM 4096
#define NEXP 64

typedef short bf16x8 __attribute__((ext_vector_type(8)));
typedef float f32x4 __attribute__((ext_vector_type(4)));

constexpr int TOK_BLK = 32;  // tokens per block -> grid 512 = 2 blocks/CU

__device__ __forceinline__ unsigned short bf16_rn(float f) {
  unsigned u = __float_as_uint(f);
  u += 0x7fffu + ((u >> 16) & 1u);
  return (unsigned short)(u >> 16);
}
__device__ __forceinline__ float bf16_tof(unsigned short h) {
  return __uint_as_float(((unsigned)h) << 16);
}

// packed hi/lo split: 8 floats -> bf16x8 hi + bf16x8 lo via v_cvt_pk_bf16_f32
__device__ __forceinline__ void split8(const float4 a, const float4 b,
                                       bf16x8& hi, bf16x8& lo) {
  const float f[8] = {a.x, a.y, a.z, a.w, b.x, b.y, b.z, b.w};
  union { unsigned u[4]; bf16x8 v; } H, L;
#pragma unroll
  for (int p = 0; p < 4; ++p) {
    const float2 fp = make_float2(f[2 * p], f[2 * p + 1]);
    const __hip_bfloat162 hh = __float22bfloat162_rn(fp);
    const unsigned uh = *(const unsigned*)&hh;
    const float h0 = __uint_as_float(uh << 16);
    const float h1 = __uint_as_float(uh & 0xffff0000u);
    const __hip_bfloat162 ll =
        __float22bfloat162_rn(make_float2(fp.x - h0, fp.y - h1));
    H.u[p] = uh;
    L.u[p] = *(const unsigned*)&ll;
  }
  hi = H.v;
  lo = L.v;
}

// ------ K0: split W into bf16 hi + lo (1 MB, once) + zero cnt (no memset) ------
__global__ __launch_bounds__(256) void k0_wsplit(const float* __restrict__ W,
                                                 unsigned short* __restrict__ hi,
                                                 unsigned short* __restrict__ lo,
                                                 int* __restrict__ cnt) {
  const int i = (blockIdx.x * 256 + threadIdx.x) * 4;
  const float4 f = *(const float4*)(W + i);
  ushort4 h, l;
  h.x = bf16_rn(f.x); l.x = bf16_rn(f.x - bf16_tof(h.x));
  h.y = bf16_rn(f.y); l.y = bf16_rn(f.y - bf16_tof(h.y));
  h.z = bf16_rn(f.z); l.z = bf16_rn(f.z - bf16_tof(h.z));
  h.w = bf16_rn(f.w); l.w = bf16_rn(f.w - bf16_tof(h.w));
  *(ushort4*)(hi + i) = h;
  *(ushort4*)(lo + i) = l;
  if (blockIdx.x < 8) {  // zero cnt[64][128] (runs before k1 in-stream)
    int4* c4 = (int4*)cnt;
    c4[blockIdx.x * 256 + threadIdx.x] = make_int4(0, 0, 0, 0);
  }
}

// ------- K1 (fused, MFMA, NO LDS in K-loop): logits + softmax + top2 + hist ----
// R14 lesson: the per-chunk __syncthreads (needed only for W-in-LDS) forces a
// vmcnt(0) drain 64x per block; with thin compute that latency is exposed.
// Here W hi/lo fragments are loaded global->reg DIRECT FROM L2 (W bf16 = 2MB,
// L2-resident; per-lane 16B, 4 lanes/row-line coalesce) and x global->reg from
// HBM; both register-double-buffered. NO barrier in the K-loop -> waves are
// independent streams; in-order vmcnt gives "wait for chunk t only" while
// t+1 stays in flight. 8 waves/CU x 4KB = 32KB outstanding >= 9KB (BW x lat)
// -> HBM saturated; cadence = 64 x 1600cy ~= 43us.
// Wave = 16 tokens (th=wid&1) x 32 experts (eh=wid>>1, 2 N-tiles).
// MFMA 16x16x32_bf16 (m89 layouts, R12-14 passed): A row=lane&15(token),
// k=(lane>>4)*8+j; B col=lane&15(expert); D col=lane&15, row=(lane>>4)*4+reg.
__global__ __launch_bounds__(256, 2) void k1_fused(
    const float* __restrict__ x, const unsigned short* __restrict__ Whi,
    const unsigned short* __restrict__ Wlo, float* __restrict__ topw,
    int* __restrict__ sel, int* __restrict__ cnt) {
  __shared__ float lg[TOK_BLK * 68];  // 8.7 KB (epilogue only)
  __shared__ int hist[NEXP];

  const int tid = threadIdx.x;
  const int lane = tid & 63;
  const int wid = __builtin_amdgcn_readfirstlane(tid >> 6);  // wave 0..3
  const int th = wid & 1;   // token half
  const int eh = wid >> 1;  // expert half
  const int r = lane & 15;  // A token row / B expert col within tile
  const int g = lane >> 4;  // k-group
  const int tok0 = blockIdx.x * TOK_BLK;

  f32x4 acc[2] = {};  // 2 N-tiles

  const float* xbase = x + (size_t)(tok0 + th * 16 + r) * DIM + g * 8;
  const size_t w0 = (size_t)(eh * 32 + r) * DIM + g * 8;        // nt=0 row
  const size_t w1 = (size_t)(eh * 32 + 16 + r) * DIM + g * 8;   // nt=1 row

  auto xload = [&](float4* xd, int t) {
    const float* p = xbase + t * 64;
    xd[0] = *(const float4*)(p);
    xd[1] = *(const float4*)(p + 4);
    xd[2] = *(const float4*)(p + 32);
    xd[3] = *(const float4*)(p + 36);
  };
  // wf[nt][h] fragment loads (hi and lo planes)
  auto wload = [&](bf16x8 wh[2][2], bf16x8 wl[2][2], int t) {
#pragma unroll
    for (int h = 0; h < 2; ++h) {
      wh[0][h] = *(const bf16x8*)(Whi + w0 + t * 64 + h * 32);
      wl[0][h] = *(const bf16x8*)(Wlo + w0 + t * 64 + h * 32);
      wh[1][h] = *(const bf16x8*)(Whi + w1 + t * 64 + h * 32);
      wl[1][h] = *(const bf16x8*)(Wlo + w1 + t * 64 + h * 32);
    }
  };
  auto compute = [&](const float4* xc, bf16x8 wh[2][2], bf16x8 wl[2][2]) {
#pragma unroll
    for (int h = 0; h < 2; ++h) {
      bf16x8 Ahi, Alo;
      split8(xc[2 * h], xc[2 * h + 1], Ahi, Alo);
#pragma unroll
      for (int nt = 0; nt < 2; ++nt) {
        acc[nt] = __builtin_amdgcn_mfma_f32_16x16x32_bf16(Ahi, wh[nt][h], acc[nt], 0, 0, 0);
        acc[nt] = __builtin_amdgcn_mfma_f32_16x16x32_bf16(Alo, wh[nt][h], acc[nt], 0, 0, 0);
        acc[nt] = __builtin_amdgcn_mfma_f32_16x16x32_bf16(Ahi, wl[nt][h], acc[nt], 0, 0, 0);
      }
    }
  };

  float4 xA[4], xB[4];
  bf16x8 whA[2][2], wlA[2][2], whB[2][2], wlB[2][2];
  xload(xA, 0);
  wload(whA, wlA, 0);

  for (int t = 0; t < 64; t += 2) {
    if (t + 1 < 64) {
      xload(xB, t + 1);
      wload(whB, wlB, t + 1);
    }
    compute(xA, whA, wlA);
    if (t + 2 < 64) {
      xload(xA, t + 2);
      wload(whA, wlA, t + 2);
    }
    compute(xB, whB, wlB);
  }

  // epilogue: publish logits to LDS
  if (tid < NEXP) hist[tid] = 0;
  // D: token = th*16 + g*4 + rg, expert = eh*32 + nt*16 + r
#pragma unroll
  for (int nt = 0; nt < 2; ++nt)
#pragma unroll
    for (int rg = 0; rg < 4; ++rg)
      lg[(th * 16 + g * 4 + rg) * 68 + eh * 32 + nt * 16 + r] = acc[nt][rg];
  __syncthreads();

  // softmax + top2 per token (threads 0..31), then histogram
  if (tid < TOK_BLK) {
    const float* rowp = lg + tid * 68;
    float4 v[16];
#pragma unroll
    for (int c = 0; c < 16; ++c) v[c] = *(const float4*)(rowp + c * 4);

    float v0 = -INFINITY, v1 = -INFINITY;
    int i0 = 0, i1 = 0;
#define TOP2_STEP(val, idx)                                  \
  {                                                          \
    const float vv = (val);                                  \
    const int ee = (idx);                                    \
    if (vv > v0) { v1 = v0; i1 = i0; v0 = vv; i0 = ee; }     \
    else if (vv > v1) { v1 = vv; i1 = ee; }                  \
  }
#pragma unroll
    for (int c = 0; c < 16; ++c) {
      TOP2_STEP(v[c].x, c * 4 + 0);
      TOP2_STEP(v[c].y, c * 4 + 1);
      TOP2_STEP(v[c].z, c * 4 + 2);
      TOP2_STEP(v[c].w, c * 4 + 3);
    }
#undef TOP2_STEP

    float denom = 0.f;
#pragma unroll
    for (int c = 0; c < 16; ++c) {
      denom += expf(v[c].x - v0);
      denom += expf(v[c].y - v0);
      denom += expf(v[c].z - v0);
      denom += expf(v[c].w - v0);
    }
    const float w0s = 1.0f / denom;  // expf(0)==1 exactly
    const float w1s = expf(v1 - v0) / denom;

    const int tk = tok0 + tid;
    topw[2 * tk + 0] = w0s;
    topw[2 * tk + 1] = w1s;
    sel[2 * tk + 0] = i0;
    sel[2 * tk + 1] = i1;
    atomicAdd(&hist[i0], 1);
    atomicAdd(&hist[i1], 1);
  }
  __syncthreads();
  if (tid < NEXP) {
    const int h = hist[tid];
    if (h) atomicAdd(&cnt[tid * 128 + (blockIdx.x >> 2)], h);  // cnt[e][chunk]
  }
}

// -------- K3: expert totals (counts out), exclusive offsets, chunk bases --------
__global__ void k3_scan(const int* __restrict__ cnt, int* __restrict__ cb,
                        float* __restrict__ counts_out) {
  __shared__ int tot[NEXP];
  const int e = threadIdx.x;  // 64 threads
  const int4* row4 = (const int4*)(cnt + e * 128);
  int run = 0;
#pragma unroll
  for (int q = 0; q < 32; ++q) {
    const int4 v = row4[q];
    run += v.x + v.y + v.z + v.w;
  }
  tot[e] = run;
  counts_out[e] = (float)run;
  __syncthreads();
  int g = 0;
  for (int q = 0; q < e; ++q) g += tot[q];
  int r = g;
  for (int p = 0; p < 128; ++p) {
    cb[p * NEXP + e] = r;
    r += cnt[e * 128 + p];
  }
}

// ---------------- K4: stable scatter (counting-sort permutation) ----------------
__global__ __launch_bounds__(256) void k4_scatter(const int* __restrict__ sel,
                                                  const int* __restrict__ cb,
                                                  float* __restrict__ gout) {
  __shared__ int wcnt[4 * NEXP];
  const int tid = threadIdx.x;
  const int s = blockIdx.x * 256 + tid;
  const int e = sel[s];
  const int lane = tid & 63;
  const int wv = tid >> 6;
  wcnt[tid] = 0;
  __syncthreads();

  unsigned long long mask = ~0ull;
#pragma unroll
  for (int b = 0; b < 6; ++b) {
    const unsigned long long bb = __ballot((e >> b) & 1);
    mask &= ((e >> b) & 1) ? bb : ~bb;
  }
  const unsigned long long below = mask & ((1ull << lane) - 1ull);
  const int wr = __popcll(below);
  if (wr == 0) wcnt[wv * NEXP + e] = __popcll(mask);
  __syncthreads();

  int base = cb[blockIdx.x * NEXP + e];
  for (int w2 = 0; w2 < wv; ++w2) base += wcnt[w2 * NEXP + e];
  gout[base + wr] = (float)s;
}

extern "C" void kernel_launch(void* const* d_in, const int* in_sizes, int n_in,
                              void* d_out, int out_size, void* d_ws, size_t ws_size,
                              hipStream_t stream) {
  const float* x = (const float*)d_in[0];
  const float* W = (const float*)d_in[1];
  float* out = (float*)d_out;

  unsigned short* whi_g = (unsigned short*)d_ws;  // 512 KB
  unsigned short* wlo_g = whi_g + NEXP * DIM;     // 512 KB
  int* sel = (int*)(wlo_g + NEXP * DIM);          // 128 KB
  int* cnt = sel + N_TOKENS * 2;                  // 32 KB (cnt[e][128])
  int* cb = cnt + 128 * NEXP;                     // 32 KB (cb[p][e])

  hipLaunchKernelGGL(k0_wsplit, dim3((NEXP * DIM) / 1024), dim3(256), 0, stream,
                     W, whi_g, wlo_g, cnt);
  hipLaunchKernelGGL(k1_fused, dim3(N_TOKENS / TOK_BLK), dim3(256), 0, stream,
                     x, whi_g, wlo_g, out, sel, cnt);
  hipLaunchKernelGGL(k3_scan, dim3(1), dim3(64), 0, stream, cnt, cb,
                     out + 2 * N_TOKENS + 2 * N_TOKENS);
  hipLaunchKernelGGL(k4_scatter, dim3((2 * N_TOKENS) / 256), dim3(256), 0, stream,
                     sel, cb, out + 2 * N_TOKENS);
}

// Round 16
// 94.678 us; speedup vs baseline: 2.0503x; 2.0503x over previous
//
#include <hip/hip_runtime.h>
#include <hip/hip_bf16.h>
#include <math.h>
#include <stdint.h>

#define N_TOKENS 16384
#define DIM 4096
#define NEXP 64

typedef const __attribute__((address_space(1))) void gvoid_t;
typedef __attribute__((address_space(3))) void svoid_t;
typedef short bf16x8 __attribute__((ext_vector_type(8)));
typedef float f32x4 __attribute__((ext_vector_type(4)));

constexpr int TOK_BLK = 32;  // tokens per block -> grid 512 = 2 blocks/CU

__device__ __forceinline__ unsigned short bf16_rn(float f) {
  unsigned u = __float_as_uint(f);
  u += 0x7fffu + ((u >> 16) & 1u);
  return (unsigned short)(u >> 16);
}
__device__ __forceinline__ float bf16_tof(unsigned short h) {
  return __uint_as_float(((unsigned)h) << 16);
}

// packed hi/lo split: 8 floats -> bf16x8 hi + bf16x8 lo via v_cvt_pk_bf16_f32
__device__ __forceinline__ void split8(const float4 a, const float4 b,
                                       bf16x8& hi, bf16x8& lo) {
  const float f[8] = {a.x, a.y, a.z, a.w, b.x, b.y, b.z, b.w};
  union { unsigned u[4]; bf16x8 v; } H, L;
#pragma unroll
  for (int p = 0; p < 4; ++p) {
    const float2 fp = make_float2(f[2 * p], f[2 * p + 1]);
    const __hip_bfloat162 hh = __float22bfloat162_rn(fp);
    const unsigned uh = *(const unsigned*)&hh;
    const float h0 = __uint_as_float(uh << 16);
    const float h1 = __uint_as_float(uh & 0xffff0000u);
    const __hip_bfloat162 ll =
        __float22bfloat162_rn(make_float2(fp.x - h0, fp.y - h1));
    H.u[p] = uh;
    L.u[p] = *(const unsigned*)&ll;
  }
  hi = H.v;
  lo = L.v;
}

// ------ K0: split W into bf16 hi + lo (1 MB, once) + zero cnt (no memset) ------
__global__ __launch_bounds__(256) void k0_wsplit(const float* __restrict__ W,
                                                 unsigned short* __restrict__ hi,
                                                 unsigned short* __restrict__ lo,
                                                 int* __restrict__ cnt) {
  const int i = (blockIdx.x * 256 + threadIdx.x) * 4;
  const float4 f = *(const float4*)(W + i);
  ushort4 h, l;
  h.x = bf16_rn(f.x); l.x = bf16_rn(f.x - bf16_tof(h.x));
  h.y = bf16_rn(f.y); l.y = bf16_rn(f.y - bf16_tof(h.y));
  h.z = bf16_rn(f.z); l.z = bf16_rn(f.z - bf16_tof(h.z));
  h.w = bf16_rn(f.w); l.w = bf16_rn(f.w - bf16_tof(h.w));
  *(ushort4*)(hi + i) = h;
  *(ushort4*)(lo + i) = l;
  if (blockIdx.x < 8) {  // zero cnt[64][128] (runs before k1 in-stream)
    int4* c4 = (int4*)cnt;
    c4[blockIdx.x * 256 + threadIdx.x] = make_int4(0, 0, 0, 0);
  }
}

// ------- K1 (fused, MFMA, T3/T4 2-phase): logits + softmax + top2 + hist -------
// The R13/R14 stall was __syncthreads' implicit vmcnt(0) drain (64x/block);
// R15's reg-staged fix was de-pipelined by the compiler (VGPR 64). Here:
// LDS-staged (can't be sunk) + COUNTED vmcnt + raw barriers (T3/T4):
//   iter t: stage(t+1) [6 glds] ; s_waitcnt vmcnt(6)  <- waits stage(t) ONLY,
//   stage(t+1) stays in flight across the barrier ; s_barrier ; compute(t) ;
//   s_barrier.  No vmcnt(0) in the loop.
// x fp32 staged with slot-XOR s^(row&15) (R11/12-verified); W hi/lo bf16 with
// s^(row&7) (R13-verified). Wave = 16 tokens (th) x 32 experts (eh, 2 tiles).
// MFMA 16x16x32_bf16, m89 layouts (R12-15 passed).
__global__ __launch_bounds__(256, 2) void k1_fused(
    const float* __restrict__ x, const unsigned short* __restrict__ Whi,
    const unsigned short* __restrict__ Wlo, float* __restrict__ topw,
    int* __restrict__ sel, int* __restrict__ cnt) {
  __shared__ __align__(16) unsigned char smem[49152 + 256];
  float* const x0 = (float*)smem;                               // 8 KB
  float* const x1 = (float*)(smem + 8192);                      // 8 KB
  unsigned short* const wh0 = (unsigned short*)(smem + 16384);  // 8 KB
  unsigned short* const wl0 = (unsigned short*)(smem + 24576);  // 8 KB
  unsigned short* const wh1 = (unsigned short*)(smem + 32768);  // 8 KB
  unsigned short* const wl1 = (unsigned short*)(smem + 40960);  // 8 KB
  float* const lg = (float*)smem;          // overlay after K-loop (8.7 KB)
  int* const hist = (int*)(smem + 49152);  // 256 B

  const int tid = threadIdx.x;
  const int lane = tid & 63;
  const int wid = __builtin_amdgcn_readfirstlane(tid >> 6);  // wave 0..3
  const int th = wid & 1;   // token half
  const int eh = wid >> 1;  // expert half
  const int r = lane & 15;  // A token row / B expert col within tile
  const int g = lane >> 4;  // k-group
  const int tok0 = blockIdx.x * TOK_BLK;

  f32x4 acc[2] = {};  // 2 N-tiles

  // stage one 64-k chunk: x 2 glds + Whi 2 + Wlo 2 = 6 glds/wave
  auto stage = [&](float* xd, unsigned short* whd, unsigned short* wld,
                   int kc) {
#pragma unroll
    for (int q = 0; q < 2; ++q) {  // x: 4 rows x 16 slots per glds
      const int r0 = wid * 8 + q * 4;
      const int row = r0 + (lane >> 4);
      const float* src =
          x + (size_t)(tok0 + row) * DIM + kc + 4 * ((lane & 15) ^ (row & 15));
      __builtin_amdgcn_global_load_lds((gvoid_t*)src, (svoid_t*)(xd + r0 * 64),
                                       16, 0, 0);
    }
#pragma unroll
    for (int q = 0; q < 2; ++q) {  // W: 8 rows x 8 slots per glds, hi+lo
      const int r0 = wid * 16 + q * 8;
      const int row = r0 + (lane >> 3);
      const int s = (lane & 7) ^ (row & 7);
      __builtin_amdgcn_global_load_lds(
          (gvoid_t*)(Whi + (size_t)row * DIM + kc + 8 * s),
          (svoid_t*)(whd + r0 * 64), 16, 0, 0);
      __builtin_amdgcn_global_load_lds(
          (gvoid_t*)(Wlo + (size_t)row * DIM + kc + 8 * s),
          (svoid_t*)(wld + r0 * 64), 16, 0, 0);
    }
  };

  auto compute = [&](const float* xb, const unsigned short* whb,
                     const unsigned short* wlb) {
    const int xrow = th * 16 + r;
#pragma unroll
    for (int h = 0; h < 2; ++h) {
      const int s0 = h * 8 + 2 * g;
      const float4 fa = *(const float4*)(xb + xrow * 64 + 4 * (s0 ^ (xrow & 15)));
      const float4 fb =
          *(const float4*)(xb + xrow * 64 + 4 * ((s0 + 1) ^ (xrow & 15)));
      bf16x8 Ahi, Alo;
      split8(fa, fb, Ahi, Alo);
#pragma unroll
      for (int nt = 0; nt < 2; ++nt) {
        const int wrow = eh * 32 + nt * 16 + r;
        const int wadr = wrow * 64 + 8 * ((h * 4 + g) ^ (wrow & 7));
        const bf16x8 Bhi = *(const bf16x8*)(whb + wadr);
        const bf16x8 Blo = *(const bf16x8*)(wlb + wadr);
        acc[nt] = __builtin_amdgcn_mfma_f32_16x16x32_bf16(Ahi, Bhi, acc[nt], 0, 0, 0);
        acc[nt] = __builtin_amdgcn_mfma_f32_16x16x32_bf16(Alo, Bhi, acc[nt], 0, 0, 0);
        acc[nt] = __builtin_amdgcn_mfma_f32_16x16x32_bf16(Ahi, Blo, acc[nt], 0, 0, 0);
      }
    }
  };

  stage(x0, wh0, wl0, 0);
  for (int t = 0; t < 64; t += 2) {
    // ---- iter t (compute buf0) ----
    if (t + 1 < 64) {
      stage(x1, wh1, wl1, (t + 1) * 64);
      asm volatile("s_waitcnt vmcnt(6)" ::: "memory");  // stage(t) landed
    } else {
      asm volatile("s_waitcnt vmcnt(0)" ::: "memory");
    }
    __builtin_amdgcn_sched_barrier(0);
    __builtin_amdgcn_s_barrier();  // all waves' stage(t) visible
    compute(x0, wh0, wl0);
    __builtin_amdgcn_s_barrier();  // readers done before buf0 rewrite
    __builtin_amdgcn_sched_barrier(0);
    // ---- iter t+1 (compute buf1) ----
    if (t + 2 < 64) {
      stage(x0, wh0, wl0, (t + 2) * 64);
      asm volatile("s_waitcnt vmcnt(6)" ::: "memory");  // stage(t+1) landed
    } else {
      asm volatile("s_waitcnt vmcnt(0)" ::: "memory");
    }
    __builtin_amdgcn_sched_barrier(0);
    __builtin_amdgcn_s_barrier();
    compute(x1, wh1, wl1);
    __builtin_amdgcn_s_barrier();
    __builtin_amdgcn_sched_barrier(0);
  }

  // epilogue: publish logits (lg overlays the staging buffers)
  if (tid < NEXP) hist[tid] = 0;
  // D: token = th*16 + g*4 + rg, expert = eh*32 + nt*16 + r
#pragma unroll
  for (int nt = 0; nt < 2; ++nt)
#pragma unroll
    for (int rg = 0; rg < 4; ++rg)
      lg[(th * 16 + g * 4 + rg) * 68 + eh * 32 + nt * 16 + r] = acc[nt][rg];
  __syncthreads();

  // softmax + top2 per token (threads 0..31), then histogram
  if (tid < TOK_BLK) {
    const float* rowp = lg + tid * 68;
    float4 v[16];
#pragma unroll
    for (int c = 0; c < 16; ++c) v[c] = *(const float4*)(rowp + c * 4);

    float v0 = -INFINITY, v1 = -INFINITY;
    int i0 = 0, i1 = 0;
#define TOP2_STEP(val, idx)                                  \
  {                                                          \
    const float vv = (val);                                  \
    const int ee = (idx);                                    \
    if (vv > v0) { v1 = v0; i1 = i0; v0 = vv; i0 = ee; }     \
    else if (vv > v1) { v1 = vv; i1 = ee; }                  \
  }
#pragma unroll
    for (int c = 0; c < 16; ++c) {
      TOP2_STEP(v[c].x, c * 4 + 0);
      TOP2_STEP(v[c].y, c * 4 + 1);
      TOP2_STEP(v[c].z, c * 4 + 2);
      TOP2_STEP(v[c].w, c * 4 + 3);
    }
#undef TOP2_STEP

    float denom = 0.f;
#pragma unroll
    for (int c = 0; c < 16; ++c) {
      denom += expf(v[c].x - v0);
      denom += expf(v[c].y - v0);
      denom += expf(v[c].z - v0);
      denom += expf(v[c].w - v0);
    }
    const float w0s = 1.0f / denom;  // expf(0)==1 exactly
    const float w1s = expf(v1 - v0) / denom;

    const int tk = tok0 + tid;
    topw[2 * tk + 0] = w0s;
    topw[2 * tk + 1] = w1s;
    sel[2 * tk + 0] = i0;
    sel[2 * tk + 1] = i1;
    atomicAdd(&hist[i0], 1);
    atomicAdd(&hist[i1], 1);
  }
  __syncthreads();
  if (tid < NEXP) {
    const int h = hist[tid];
    if (h) atomicAdd(&cnt[tid * 128 + (blockIdx.x >> 2)], h);  // cnt[e][chunk]
  }
}

// -------- K3: expert totals (counts out), exclusive offsets, chunk bases --------
__global__ void k3_scan(const int* __restrict__ cnt, int* __restrict__ cb,
                        float* __restrict__ counts_out) {
  __shared__ int tot[NEXP];
  const int e = threadIdx.x;  // 64 threads
  const int4* row4 = (const int4*)(cnt + e * 128);
  int run = 0;
#pragma unroll
  for (int q = 0; q < 32; ++q) {
    const int4 v = row4[q];
    run += v.x + v.y + v.z + v.w;
  }
  tot[e] = run;
  counts_out[e] = (float)run;
  __syncthreads();
  int g = 0;
  for (int q = 0; q < e; ++q) g += tot[q];
  int r = g;
  for (int p = 0; p < 128; ++p) {
    cb[p * NEXP + e] = r;
    r += cnt[e * 128 + p];
  }
}

// ---------------- K4: stable scatter (counting-sort permutation) ----------------
__global__ __launch_bounds__(256) void k4_scatter(const int* __restrict__ sel,
                                                  const int* __restrict__ cb,
                                                  float* __restrict__ gout) {
  __shared__ int wcnt[4 * NEXP];
  const int tid = threadIdx.x;
  const int s = blockIdx.x * 256 + tid;
  const int e = sel[s];
  const int lane = tid & 63;
  const int wv = tid >> 6;
  wcnt[tid] = 0;
  __syncthreads();

  unsigned long long mask = ~0ull;
#pragma unroll
  for (int b = 0; b < 6; ++b) {
    const unsigned long long bb = __ballot((e >> b) & 1);
    mask &= ((e >> b) & 1) ? bb : ~bb;
  }
  const unsigned long long below = mask & ((1ull << lane) - 1ull);
  const int wr = __popcll(below);
  if (wr == 0) wcnt[wv * NEXP + e] = __popcll(mask);
  __syncthreads();

  int base = cb[blockIdx.x * NEXP + e];
  for (int w2 = 0; w2 < wv; ++w2) base += wcnt[w2 * NEXP + e];
  gout[base + wr] = (float)s;
}

extern "C" void kernel_launch(void* const* d_in, const int* in_sizes, int n_in,
                              void* d_out, int out_size, void* d_ws, size_t ws_size,
                              hipStream_t stream) {
  const float* x = (const float*)d_in[0];
  const float* W = (const float*)d_in[1];
  float* out = (float*)d_out;

  unsigned short* whi_g = (unsigned short*)d_ws;  // 512 KB
  unsigned short* wlo_g = whi_g + NEXP * DIM;     // 512 KB
  int* sel = (int*)(wlo_g + NEXP * DIM);          // 128 KB
  int* cnt = sel + N_TOKENS * 2;                  // 32 KB (cnt[e][128])
  int* cb = cnt + 128 * NEXP;                     // 32 KB (cb[p][e])

  hipLaunchKernelGGL(k0_wsplit, dim3((NEXP * DIM) / 1024), dim3(256), 0, stream,
                     W, whi_g, wlo_g, cnt);
  hipLaunchKernelGGL(k1_fused, dim3(N_TOKENS / TOK_BLK), dim3(256), 0, stream,
                     x, whi_g, wlo_g, out, sel, cnt);
  hipLaunchKernelGGL(k3_scan, dim3(1), dim3(64), 0, stream, cnt, cb,
                     out + 2 * N_TOKENS + 2 * N_TOKENS);
  hipLaunchKernelGGL(k4_scatter, dim3((2 * N_TOKENS) / 256), dim3(256), 0, stream,
                     sel, cb, out + 2 * N_TOKENS);
}

// Round 17
// 94.229 us; speedup vs baseline: 2.0600x; 1.0048x over previous
//
#include <hip/hip_runtime.h>
#include <hip/hip_bf16.h>
#include <math.h>
#include <stdint.h>

#define N_TOKENS 16384
#define DIM 4096
#define NEXP 64

typedef const __attribute__((address_space(1))) void gvoid_t;
typedef __attribute__((address_space(3))) void svoid_t;
typedef short bf16x8 __attribute__((ext_vector_type(8)));
typedef float f32x4 __attribute__((ext_vector_type(4)));

constexpr int TOK_BLK = 16;  // tokens per block -> grid 1024 = 4 blocks/CU

__device__ __forceinline__ unsigned short bf16_rn(float f) {
  unsigned u = __float_as_uint(f);
  u += 0x7fffu + ((u >> 16) & 1u);
  return (unsigned short)(u >> 16);
}
__device__ __forceinline__ float bf16_tof(unsigned short h) {
  return __uint_as_float(((unsigned)h) << 16);
}

// packed hi/lo split: 8 floats -> bf16x8 hi + bf16x8 lo via v_cvt_pk_bf16_f32
__device__ __forceinline__ void split8(const float4 a, const float4 b,
                                       bf16x8& hi, bf16x8& lo) {
  const float f[8] = {a.x, a.y, a.z, a.w, b.x, b.y, b.z, b.w};
  union { unsigned u[4]; bf16x8 v; } H, L;
#pragma unroll
  for (int p = 0; p < 4; ++p) {
    const float2 fp = make_float2(f[2 * p], f[2 * p + 1]);
    const __hip_bfloat162 hh = __float22bfloat162_rn(fp);
    const unsigned uh = *(const unsigned*)&hh;
    const float h0 = __uint_as_float(uh << 16);
    const float h1 = __uint_as_float(uh & 0xffff0000u);
    const __hip_bfloat162 ll =
        __float22bfloat162_rn(make_float2(fp.x - h0, fp.y - h1));
    H.u[p] = uh;
    L.u[p] = *(const unsigned*)&ll;
  }
  hi = H.v;
  lo = L.v;
}

// ------ K0: split W into bf16 hi + lo (1 MB, once) + zero cnt (no memset) ------
__global__ __launch_bounds__(256) void k0_wsplit(const float* __restrict__ W,
                                                 unsigned short* __restrict__ hi,
                                                 unsigned short* __restrict__ lo,
                                                 int* __restrict__ cnt) {
  const int i = (blockIdx.x * 256 + threadIdx.x) * 4;
  const float4 f = *(const float4*)(W + i);
  ushort4 h, l;
  h.x = bf16_rn(f.x); l.x = bf16_rn(f.x - bf16_tof(h.x));
  h.y = bf16_rn(f.y); l.y = bf16_rn(f.y - bf16_tof(h.y));
  h.z = bf16_rn(f.z); l.z = bf16_rn(f.z - bf16_tof(h.z));
  h.w = bf16_rn(f.w); l.w = bf16_rn(f.w - bf16_tof(h.w));
  *(ushort4*)(hi + i) = h;
  *(ushort4*)(lo + i) = l;
  if (blockIdx.x < 8) {  // zero cnt[64][128] (runs before k1 in-stream)
    int4* c4 = (int4*)cnt;
    c4[blockIdx.x * 256 + threadIdx.x] = make_int4(0, 0, 0, 0);
  }
}

// ------- K1 (fused, MFMA, T3/T4 2-phase): logits + softmax + top2 + hist -------
// R16 structure (counted vmcnt, raw barriers, no vmcnt(0) in loop) at finer
// grain: TOK_BLK=16, grid 1024 = 4 blocks/CU (LDS exactly 40960 B), so
// block-level interleave covers each block's barrier window — R16's residual.
// stage = 5 glds/wave (x 1, Whi 2, Wlo 2) -> s_waitcnt vmcnt(5) waits chunk t
// only while chunk t+1 stays in flight across the barrier.
// Wave = 16 tokens x 16 experts (nt = wid). MFMA 16x16x32_bf16, m89 layouts
// (R12-16 passed): A row=lane&15(token); B col=lane&15(expert);
// D col=lane&15, row=(lane>>4)*4+reg.
__global__ __launch_bounds__(256, 4) void k1_fused(
    const float* __restrict__ x, const unsigned short* __restrict__ Whi,
    const unsigned short* __restrict__ Wlo, float* __restrict__ topw,
    int* __restrict__ sel, int* __restrict__ cnt) {
  __shared__ __align__(16) unsigned char smem[40960];
  float* const x0 = (float*)smem;                               // 4 KB
  float* const x1 = (float*)(smem + 4096);                      // 4 KB
  unsigned short* const wh0 = (unsigned short*)(smem + 8192);   // 8 KB
  unsigned short* const wh1 = (unsigned short*)(smem + 16384);  // 8 KB
  unsigned short* const wl0 = (unsigned short*)(smem + 24576);  // 8 KB
  unsigned short* const wl1 = (unsigned short*)(smem + 32768);  // 8 KB
  float* const lg = (float*)smem;          // overlay after K-loop (4.3 KB)
  int* const hist = (int*)(smem + 4608);   // 256 B (within x region)

  const int tid = threadIdx.x;
  const int lane = tid & 63;
  const int wid = __builtin_amdgcn_readfirstlane(tid >> 6);  // wave = N-tile
  const int r = lane & 15;  // A token row / B expert col within tile
  const int g = lane >> 4;  // k-group
  const int tok0 = blockIdx.x * TOK_BLK;

  f32x4 acc = {};  // one 16-expert N-tile

  // stage one 64-k chunk: x 1 glds + Whi 2 + Wlo 2 = 5 glds/wave
  auto stage = [&](float* xd, unsigned short* whd, unsigned short* wld,
                   int kc) {
    {  // x: 4 rows x 16 slots (1 KB), rows wid*4..+4
      const int r0 = wid * 4;
      const int row = r0 + (lane >> 4);
      const float* src =
          x + (size_t)(tok0 + row) * DIM + kc + 4 * ((lane & 15) ^ (row & 15));
      __builtin_amdgcn_global_load_lds((gvoid_t*)src, (svoid_t*)(xd + r0 * 64),
                                       16, 0, 0);
    }
#pragma unroll
    for (int q = 0; q < 2; ++q) {  // W: 8 rows x 8 slots per glds, hi+lo
      const int r0 = wid * 16 + q * 8;
      const int row = r0 + (lane >> 3);
      const int s = (lane & 7) ^ (row & 7);
      __builtin_amdgcn_global_load_lds(
          (gvoid_t*)(Whi + (size_t)row * DIM + kc + 8 * s),
          (svoid_t*)(whd + r0 * 64), 16, 0, 0);
      __builtin_amdgcn_global_load_lds(
          (gvoid_t*)(Wlo + (size_t)row * DIM + kc + 8 * s),
          (svoid_t*)(wld + r0 * 64), 16, 0, 0);
    }
  };

  auto compute = [&](const float* xb, const unsigned short* whb,
                     const unsigned short* wlb) {
#pragma unroll
    for (int h = 0; h < 2; ++h) {
      const int s0 = h * 8 + 2 * g;
      const float4 fa = *(const float4*)(xb + r * 64 + 4 * (s0 ^ r));
      const float4 fb = *(const float4*)(xb + r * 64 + 4 * ((s0 + 1) ^ r));
      bf16x8 Ahi, Alo;
      split8(fa, fb, Ahi, Alo);
      const int wrow = wid * 16 + r;
      const int wadr = wrow * 64 + 8 * ((h * 4 + g) ^ (wrow & 7));
      const bf16x8 Bhi = *(const bf16x8*)(whb + wadr);
      const bf16x8 Blo = *(const bf16x8*)(wlb + wadr);
      acc = __builtin_amdgcn_mfma_f32_16x16x32_bf16(Ahi, Bhi, acc, 0, 0, 0);
      acc = __builtin_amdgcn_mfma_f32_16x16x32_bf16(Alo, Bhi, acc, 0, 0, 0);
      acc = __builtin_amdgcn_mfma_f32_16x16x32_bf16(Ahi, Blo, acc, 0, 0, 0);
    }
  };

  stage(x0, wh0, wl0, 0);
  for (int t = 0; t < 64; t += 2) {
    // ---- iter t (compute buf0) ----
    if (t + 1 < 64) {
      stage(x1, wh1, wl1, (t + 1) * 64);
      asm volatile("s_waitcnt vmcnt(5)" ::: "memory");  // stage(t) landed
    } else {
      asm volatile("s_waitcnt vmcnt(0)" ::: "memory");
    }
    __builtin_amdgcn_sched_barrier(0);
    __builtin_amdgcn_s_barrier();  // all waves' stage(t) visible
    compute(x0, wh0, wl0);
    __builtin_amdgcn_s_barrier();  // readers done before buf0 rewrite
    __builtin_amdgcn_sched_barrier(0);
    // ---- iter t+1 (compute buf1) ----
    if (t + 2 < 64) {
      stage(x0, wh0, wl0, (t + 2) * 64);
      asm volatile("s_waitcnt vmcnt(5)" ::: "memory");  // stage(t+1) landed
    } else {
      asm volatile("s_waitcnt vmcnt(0)" ::: "memory");
    }
    __builtin_amdgcn_sched_barrier(0);
    __builtin_amdgcn_s_barrier();
    compute(x1, wh1, wl1);
    __builtin_amdgcn_s_barrier();
    __builtin_amdgcn_sched_barrier(0);
  }

  // epilogue: publish logits (lg/hist overlay the x staging buffers)
  if (tid < NEXP) hist[tid] = 0;
  // D: token = g*4 + rg, expert = wid*16 + r
#pragma unroll
  for (int rg = 0; rg < 4; ++rg)
    lg[(g * 4 + rg) * 68 + wid * 16 + r] = acc[rg];
  __syncthreads();

  // softmax + top2 per token (threads 0..15), then histogram
  if (tid < TOK_BLK) {
    const float* rowp = lg + tid * 68;
    float4 v[16];
#pragma unroll
    for (int c = 0; c < 16; ++c) v[c] = *(const float4*)(rowp + c * 4);

    float v0 = -INFINITY, v1 = -INFINITY;
    int i0 = 0, i1 = 0;
#define TOP2_STEP(val, idx)                                  \
  {                                                          \
    const float vv = (val);                                  \
    const int ee = (idx);                                    \
    if (vv > v0) { v1 = v0; i1 = i0; v0 = vv; i0 = ee; }     \
    else if (vv > v1) { v1 = vv; i1 = ee; }                  \
  }
#pragma unroll
    for (int c = 0; c < 16; ++c) {
      TOP2_STEP(v[c].x, c * 4 + 0);
      TOP2_STEP(v[c].y, c * 4 + 1);
      TOP2_STEP(v[c].z, c * 4 + 2);
      TOP2_STEP(v[c].w, c * 4 + 3);
    }
#undef TOP2_STEP

    float denom = 0.f;
#pragma unroll
    for (int c = 0; c < 16; ++c) {
      denom += expf(v[c].x - v0);
      denom += expf(v[c].y - v0);
      denom += expf(v[c].z - v0);
      denom += expf(v[c].w - v0);
    }
    const float w0s = 1.0f / denom;  // expf(0)==1 exactly
    const float w1s = expf(v1 - v0) / denom;

    const int tk = tok0 + tid;
    topw[2 * tk + 0] = w0s;
    topw[2 * tk + 1] = w1s;
    sel[2 * tk + 0] = i0;
    sel[2 * tk + 1] = i1;
    atomicAdd(&hist[i0], 1);
    atomicAdd(&hist[i1], 1);
  }
  __syncthreads();
  if (tid < NEXP) {
    const int h = hist[tid];
    if (h) atomicAdd(&cnt[tid * 128 + (blockIdx.x >> 3)], h);  // cnt[e][chunk]
  }
}

// ------ K4 (merged scan+scatter): stable counting-sort permutation + counts ----
// Each block recomputes the expert scan from cnt[e][128] in-block (32 KB L2
// reads, parallel across 128 blocks) — kills the k3 dispatch and cb buffer.
__global__ __launch_bounds__(256) void k4_scatter(const int* __restrict__ cnt,
                                                  const int* __restrict__ sel,
                                                  float* __restrict__ gout,
                                                  float* __restrict__ counts_out) {
  __shared__ int tot[NEXP], parts[NEXP], cbs[NEXP], wcnt[4 * NEXP];
  const int tid = threadIdx.x;
  const int b = blockIdx.x;
  const int s = b * 256 + tid;
  const int e = sel[s];
  const int lane = tid & 63;
  const int wv = tid >> 6;
  wcnt[tid] = 0;

  if (tid < NEXP) {
    const int4* row4 = (const int4*)(cnt + tid * 128);
    int run = 0, part = 0;
#pragma unroll
    for (int q = 0; q < 32; ++q) {
      const int4 v = row4[q];
      if (4 * q + 0 < b) part += v.x;
      if (4 * q + 1 < b) part += v.y;
      if (4 * q + 2 < b) part += v.z;
      if (4 * q + 3 < b) part += v.w;
      run += v.x + v.y + v.z + v.w;
    }
    tot[tid] = run;
    parts[tid] = part;
    if (b == 0) counts_out[tid] = (float)run;
  }
  __syncthreads();
  if (tid < NEXP) {
    int g2 = 0;
    for (int q = 0; q < tid; ++q) g2 += tot[q];
    cbs[tid] = g2 + parts[tid];
  }

  unsigned long long mask = ~0ull;
#pragma unroll
  for (int bb = 0; bb < 6; ++bb) {
    const unsigned long long bl = __ballot((e >> bb) & 1);
    mask &= ((e >> bb) & 1) ? bl : ~bl;
  }
  const unsigned long long below = mask & ((1ull << lane) - 1ull);
  const int wr = __popcll(below);
  if (wr == 0) wcnt[wv * NEXP + e] = __popcll(mask);
  __syncthreads();

  int base = cbs[e];
  for (int w2 = 0; w2 < wv; ++w2) base += wcnt[w2 * NEXP + e];
  gout[base + wr] = (float)s;
}

extern "C" void kernel_launch(void* const* d_in, const int* in_sizes, int n_in,
                              void* d_out, int out_size, void* d_ws, size_t ws_size,
                              hipStream_t stream) {
  const float* x = (const float*)d_in[0];
  const float* W = (const float*)d_in[1];
  float* out = (float*)d_out;

  unsigned short* whi_g = (unsigned short*)d_ws;  // 512 KB
  unsigned short* wlo_g = whi_g + NEXP * DIM;     // 512 KB
  int* sel = (int*)(wlo_g + NEXP * DIM);          // 128 KB
  int* cnt = sel + N_TOKENS * 2;                  // 32 KB (cnt[e][128])

  hipLaunchKernelGGL(k0_wsplit, dim3((NEXP * DIM) / 1024), dim3(256), 0, stream,
                     W, whi_g, wlo_g, cnt);
  hipLaunchKernelGGL(k1_fused, dim3(N_TOKENS / TOK_BLK), dim3(256), 0, stream,
                     x, whi_g, wlo_g, out, sel, cnt);
  hipLaunchKernelGGL(k4_scatter, dim3((2 * N_TOKENS) / 256), dim3(256), 0, stream,
                     cnt, sel, out + 2 * N_TOKENS,
                     out + 2 * N_TOKENS + 2 * N_TOKENS);
}